// Round 3
// baseline (97.551 us; speedup 1.0000x reference)
//
#include <hip/hip_runtime.h>

typedef __attribute__((ext_vector_type(8))) short bf16x8;
typedef __attribute__((ext_vector_type(4))) float f32x4;

constexpr int TN = 8192;   // tokens
constexpr int DN = 4096;   // model dim
constexpr int EN = 64;     // experts

constexpr int BM   = 32;        // rows per block
constexpr int KC   = 128;       // k per staged chunk
constexpr int NCH  = DN / KC;   // 32 chunks
constexpr int KPAD = KC + 8;    // padded LDS k-stride (bf16) -> conflict-free

__device__ __forceinline__ unsigned short f2bf(float f) {  // RNE f32->bf16
    unsigned u = __builtin_bit_cast(unsigned, f);
    u += 0x7FFFu + ((u >> 16) & 1u);
    return (unsigned short)(u >> 16);
}
__device__ __forceinline__ float bf2f(unsigned short h) {
    unsigned u = ((unsigned)h) << 16;
    return __builtin_bit_cast(float, u);
}

// Kernel 0: split wg (fp32) into hi/lo bf16 planes in ws. 64x4096 elements.
__global__ __launch_bounds__(256)
void wg_split_kernel(const float* __restrict__ wg,
                     unsigned short* __restrict__ hi,
                     unsigned short* __restrict__ lo) {
    const int i = (blockIdx.x * 256 + threadIdx.x) * 4;
    float4 v = *reinterpret_cast<const float4*>(&wg[i]);
    float f[4] = {v.x, v.y, v.z, v.w};
    unsigned short h[4], l[4];
#pragma unroll
    for (int j = 0; j < 4; ++j) {
        h[j] = f2bf(f[j]);
        l[j] = f2bf(f[j] - bf2f(h[j]));
    }
    ushort4 hv = make_ushort4(h[0], h[1], h[2], h[3]);
    ushort4 lv = make_ushort4(l[0], l[1], l[2], l[3]);
    *reinterpret_cast<ushort4*>(&hi[i]) = hv;
    *reinterpret_cast<ushort4*>(&lo[i]) = lv;
}

// Kernel 1: fused split-bf16 MFMA GEMM + top-1 softmax.
// Grid = TN/BM = 256 blocks, 512 threads (8 waves).
// Wave w: rh = w&1 (row half, 16 rows), kq = w>>1 (k-step interleave mod 4).
// x staged fp32->hi/lo bf16 into double-buffered padded LDS; wg fragments read
// directly from global (L2-hot). logits = hh + lh + hl + ll MFMA products.
__global__ __launch_bounds__(512, 1)
void gate_mfma_kernel(const float* __restrict__ x,
                      const unsigned short* __restrict__ wgh,
                      const unsigned short* __restrict__ wgl,
                      float* __restrict__ out) {
    // A[buf][plane][row][k]: 2*2*32*136*2B = 34816 B; L overlaps A after GEMM.
    __shared__ __align__(16) char smem[2 * 2 * BM * KPAD * 2];
    typedef unsigned short AType[2][BM][KPAD];
    AType* A = reinterpret_cast<AType*>(smem);                 // A[buf]
    typedef float LType[BM][EN];
    LType* L = reinterpret_cast<LType*>(smem);                 // L[kq]

    const int tid  = threadIdx.x;
    const int lane = tid & 63;
    const int w    = tid >> 6;
    const int rh   = w & 1;   // row half
    const int kq   = w >> 1;  // k-step slot (0..3)
    const int r0   = blockIdx.x * BM;

    // staging mapping: 16 threads/row, 8 contiguous floats each
    const int srow = tid >> 4;          // 0..31
    const int skf  = (tid & 15) * 8;    // float offset within chunk
    const float* xp = x + (size_t)(r0 + srow) * DN + skf;

    // fragment mapping (16x16x32): row/col = lane&15, k-chunk = (lane>>4)*8
    const int fr = lane & 15;
    const int fk = (lane >> 4) * 8;

    f32x4 acc[4] = {{0.f, 0.f, 0.f, 0.f}, {0.f, 0.f, 0.f, 0.f},
                    {0.f, 0.f, 0.f, 0.f}, {0.f, 0.f, 0.f, 0.f}};

    float4 xv0, xv1;
    auto load_chunk = [&](int t) {
        const float* p = xp + t * KC;
        xv0 = *reinterpret_cast<const float4*>(p);
        xv1 = *reinterpret_cast<const float4*>(p + 4);
    };
    auto write_chunk = [&](int b) {
        float f[8] = {xv0.x, xv0.y, xv0.z, xv0.w, xv1.x, xv1.y, xv1.z, xv1.w};
        bf16x8 vh, vl;
#pragma unroll
        for (int j = 0; j < 8; ++j) {
            unsigned short hh = f2bf(f[j]);
            vh[j] = (short)hh;
            vl[j] = (short)f2bf(f[j] - bf2f(hh));
        }
        *reinterpret_cast<bf16x8*>(&A[b][0][srow][skf]) = vh;
        *reinterpret_cast<bf16x8*>(&A[b][1][srow][skf]) = vl;
    };
    auto compute_chunk = [&](int b, int t) {
        // this wave's k-step within the chunk is slot kq (4 steps of K=32)
        const int kloc = kq * 32 + fk;
        bf16x8 ah = *reinterpret_cast<const bf16x8*>(&A[b][0][rh * 16 + fr][kloc]);
        bf16x8 al = *reinterpret_cast<const bf16x8*>(&A[b][1][rh * 16 + fr][kloc]);
        const int kg = t * KC + kloc;  // global k of fragment
#pragma unroll
        for (int et = 0; et < 4; ++et) {
            bf16x8 bh = *reinterpret_cast<const bf16x8*>(
                &wgh[(size_t)(et * 16 + fr) * DN + kg]);
            bf16x8 bl = *reinterpret_cast<const bf16x8*>(
                &wgl[(size_t)(et * 16 + fr) * DN + kg]);
            acc[et] = __builtin_amdgcn_mfma_f32_16x16x32_bf16(ah, bh, acc[et], 0, 0, 0);
            acc[et] = __builtin_amdgcn_mfma_f32_16x16x32_bf16(al, bh, acc[et], 0, 0, 0);
            acc[et] = __builtin_amdgcn_mfma_f32_16x16x32_bf16(ah, bl, acc[et], 0, 0, 0);
            acc[et] = __builtin_amdgcn_mfma_f32_16x16x32_bf16(al, bl, acc[et], 0, 0, 0);
        }
    };

    load_chunk(0);
    write_chunk(0);
    __syncthreads();
    int cur = 0;
    for (int t = 0; t < NCH; ++t) {
        if (t + 1 < NCH) load_chunk(t + 1);   // issue-early: HBM hides under MFMA
        compute_chunk(cur, t);
        if (t + 1 < NCH) {
            write_chunk(cur ^ 1);
            __syncthreads();
            cur ^= 1;
        }
    }

    // epilogue: partial logits (per kq slot) into LDS, then fused top-1 softmax
    __syncthreads();  // all waves done reading A before aliasing it as L
#pragma unroll
    for (int et = 0; et < 4; ++et)
#pragma unroll
        for (int r = 0; r < 4; ++r)
            // C/D layout: col = lane&15, row = (lane>>4)*4 + reg  [m89]
            L[kq][rh * 16 + (lane >> 4) * 4 + r][et * 16 + fr] = acc[et][r];
    __syncthreads();

    {
        const int row = tid >> 4;   // 0..31
        const int eg  = tid & 15;   // 4 experts each
        float v[4];
#pragma unroll
        for (int j = 0; j < 4; ++j) {
            float s = L[0][row][eg * 4 + j];
#pragma unroll
            for (int q = 1; q < 4; ++q) s += L[q][row][eg * 4 + j];
            v[j] = s;
        }
        float m = v[0];
        int idx = eg * 4;
#pragma unroll
        for (int j = 1; j < 4; ++j)
            if (v[j] > m) { m = v[j]; idx = eg * 4 + j; }  // strict >: first occurrence
#pragma unroll
        for (int d = 1; d < 16; d <<= 1) {
            float om = __shfl_xor(m, d);
            int   oi = __shfl_xor(idx, d);
            if (om > m || (om == m && oi < idx)) { m = om; idx = oi; }
        }
        float s = 0.0f;
#pragma unroll
        for (int j = 0; j < 4; ++j) s += __expf(v[j] - m);
#pragma unroll
        for (int d = 1; d < 16; d <<= 1) s += __shfl_xor(s, d);
        if (eg == 0) {
            out[r0 + row]      = (float)idx;
            out[TN + r0 + row] = 1.0f / s;
        }
    }
}

extern "C" void kernel_launch(void* const* d_in, const int* in_sizes, int n_in,
                              void* d_out, int out_size, void* d_ws, size_t ws_size,
                              hipStream_t stream) {
    const float* x  = (const float*)d_in[0];
    const float* wg = (const float*)d_in[1];
    float* out = (float*)d_out;

    unsigned short* wgh = (unsigned short*)d_ws;               // 64*4096 u16
    unsigned short* wgl = wgh + (size_t)EN * DN;               // +512 KB

    wg_split_kernel<<<dim3(EN * DN / (256 * 4)), dim3(256), 0, stream>>>(wg, wgh, wgl);
    gate_mfma_kernel<<<dim3(TN / BM), dim3(512), 0, stream>>>(x, wgh, wgl, out);
}

// Round 4
// 52.789 us; speedup vs baseline: 1.8479x; 1.8479x over previous
//
#include <hip/hip_runtime.h>

typedef __attribute__((ext_vector_type(8))) short bf16x8;
typedef __attribute__((ext_vector_type(4))) float f32x4;

constexpr int TN = 8192;   // tokens
constexpr int DN = 4096;   // model dim
constexpr int EN = 64;     // experts

constexpr int BM  = 32;        // rows per block
constexpr int KC  = 128;       // k per staged chunk
constexpr int NS  = DN / 32;   // 128 MFMA k-steps total
constexpr int KPB = 136;       // A k-stride in bf16 (272B row: quad stride 17 = conflict-free)

__device__ __forceinline__ unsigned short f2bf(float f) {  // RNE f32->bf16
    unsigned u = __builtin_bit_cast(unsigned, f);
    u += 0x7FFFu + ((u >> 16) & 1u);
    return (unsigned short)(u >> 16);
}
__device__ __forceinline__ float bf2f(unsigned short h) {
    unsigned u = ((unsigned)h) << 16;
    return __builtin_bit_cast(float, u);
}

// Kernel 0: split wg into hi/lo bf16 planes laid out in MFMA-fragment order:
// BF[p][s][et][lane*8+j] = plane_p( wg[et*16 + (lane&15)][s*32 + (lane>>4)*8 + j] )
// so a wave's B-fragment load in the GEMM is base + lane*16B (1KB coalesced).
__global__ __launch_bounds__(256)
void wg_frag_kernel(const float* __restrict__ wg, unsigned short* __restrict__ BF) {
    const int gid = blockIdx.x * 256 + threadIdx.x;  // 65536 items
    const int l  = gid & 63;
    const int et = (gid >> 6) & 3;
    const int s  = (gid >> 8) & (NS - 1);
    const int p  = gid >> 15;
    const int e  = et * 16 + (l & 15);
    const int k  = s * 32 + (l >> 4) * 8;

    const float* src = wg + (size_t)e * DN + k;
    float4 v0 = *reinterpret_cast<const float4*>(src);
    float4 v1 = *reinterpret_cast<const float4*>(src + 4);
    float f[8] = {v0.x, v0.y, v0.z, v0.w, v1.x, v1.y, v1.z, v1.w};
    unsigned short o[8];
#pragma unroll
    for (int j = 0; j < 8; ++j) {
        unsigned short h = f2bf(f[j]);
        o[j] = p ? f2bf(f[j] - bf2f(h)) : h;
    }
    unsigned short* dst = BF + (((size_t)p * NS + s) * 4 + et) * 512 + (size_t)l * 8;
    *reinterpret_cast<ushort4*>(dst)     = make_ushort4(o[0], o[1], o[2], o[3]);
    *reinterpret_cast<ushort4*>(dst + 4) = make_ushort4(o[4], o[5], o[6], o[7]);
}

// Kernel 1: split-bf16 MFMA GEMM partials. Grid = (TN/BM)*KSPLIT blocks, 256 thr.
// Wave = kq k-slot (4 x K=32 per 128-chunk); each wave does BOTH row halves.
// x staged fp32->hi/lo bf16 into double-buffered LDS; B fragments are single
// coalesced 16B/lane loads from the pre-swizzled BF (L2-hot, 1MB).
template <int KSPLIT>
__global__ __launch_bounds__(256, 2)
void gate_mfma_kernel(const float* __restrict__ x,
                      const unsigned short* __restrict__ BF,
                      float* __restrict__ part) {
    constexpr int KBLK = DN / KSPLIT;
    constexpr int NT   = KBLK / KC;

    __shared__ __align__(16) char smem[34816];  // A[2][2][32][KPB]u16 == L[4][32][68]f32
    typedef unsigned short AType[2][BM][KPB];
    AType* A = reinterpret_cast<AType*>(smem);

    const int tid  = threadIdx.x;
    const int lane = tid & 63;
    const int kq   = tid >> 6;          // wave id = k-slot 0..3
    const int bid  = blockIdx.x;
    const int rt   = bid / KSPLIT;
    const int ks   = bid % KSPLIT;
    const int r0   = rt * BM;
    const int k0   = ks * KBLK;
    const int s0   = k0 / 32;

    // staging: 16 threads/row, 8 contiguous floats; each thread does 2 rows
    const int srow = tid >> 4;          // 0..15 (+16 for second half)
    const int skf  = (tid & 15) * 8;
    const float* xp = x + (size_t)(r0 + srow) * DN + k0 + skf;

    const int fr  = lane & 15;          // fragment row/col
    const int fko = (lane >> 4) * 8;    // fragment k offset within K=32

    f32x4 acc[2][4] = {};

    float4 xv[2][2];
    auto g_load = [&](int t) {
        const float* p0 = xp + t * KC;
        xv[0][0] = *reinterpret_cast<const float4*>(p0);
        xv[0][1] = *reinterpret_cast<const float4*>(p0 + 4);
        const float* p1 = p0 + (size_t)16 * DN;
        xv[1][0] = *reinterpret_cast<const float4*>(p1);
        xv[1][1] = *reinterpret_cast<const float4*>(p1 + 4);
    };
    auto l_store = [&](int b) {
#pragma unroll
        for (int h = 0; h < 2; ++h) {
            float f[8] = {xv[h][0].x, xv[h][0].y, xv[h][0].z, xv[h][0].w,
                          xv[h][1].x, xv[h][1].y, xv[h][1].z, xv[h][1].w};
            bf16x8 vh, vl;
#pragma unroll
            for (int j = 0; j < 8; ++j) {
                unsigned short hh = f2bf(f[j]);
                vh[j] = (short)hh;
                vl[j] = (short)f2bf(f[j] - bf2f(hh));
            }
            *reinterpret_cast<bf16x8*>(&A[b][0][srow + h * 16][skf]) = vh;
            *reinterpret_cast<bf16x8*>(&A[b][1][srow + h * 16][skf]) = vl;
        }
    };
    auto compute = [&](int b, int t) {
        const int s = s0 + t * 4 + kq;
        const unsigned short* bp = BF + (size_t)s * (4 * 512) + (size_t)lane * 8;
        bf16x8 bh[4], bl[4];
#pragma unroll
        for (int et = 0; et < 4; ++et)
            bh[et] = *reinterpret_cast<const bf16x8*>(bp + et * 512);
#pragma unroll
        for (int et = 0; et < 4; ++et)
            bl[et] = *reinterpret_cast<const bf16x8*>(bp + (size_t)NS * 2048 + et * 512);
        bf16x8 ah[2], al[2];
#pragma unroll
        for (int rh = 0; rh < 2; ++rh) {
            ah[rh] = *reinterpret_cast<const bf16x8*>(&A[b][0][rh * 16 + fr][kq * 32 + fko]);
            al[rh] = *reinterpret_cast<const bf16x8*>(&A[b][1][rh * 16 + fr][kq * 32 + fko]);
        }
#pragma unroll
        for (int rh = 0; rh < 2; ++rh)
#pragma unroll
            for (int et = 0; et < 4; ++et) {
                acc[rh][et] = __builtin_amdgcn_mfma_f32_16x16x32_bf16(ah[rh], bh[et], acc[rh][et], 0, 0, 0);
                acc[rh][et] = __builtin_amdgcn_mfma_f32_16x16x32_bf16(al[rh], bh[et], acc[rh][et], 0, 0, 0);
                acc[rh][et] = __builtin_amdgcn_mfma_f32_16x16x32_bf16(ah[rh], bl[et], acc[rh][et], 0, 0, 0);
                acc[rh][et] = __builtin_amdgcn_mfma_f32_16x16x32_bf16(al[rh], bl[et], acc[rh][et], 0, 0, 0);
            }
    };

    g_load(0);
    l_store(0);
    __syncthreads();
    int cur = 0;
    for (int t = 0; t < NT; ++t) {
        if (t + 1 < NT) g_load(t + 1);   // issue early: HBM hides under MFMA+other block
        compute(cur, t);
        if (t + 1 < NT) {
            l_store(cur ^ 1);
            __syncthreads();
            cur ^= 1;
        }
    }

    // cross-wave k-reduction via LDS (alias A), then coalesced partial store
    __syncthreads();
    typedef float LType[BM][68];        // row stride 68 words -> 2-way max (free)
    LType* L = reinterpret_cast<LType*>(smem);
#pragma unroll
    for (int rh = 0; rh < 2; ++rh)
#pragma unroll
        for (int et = 0; et < 4; ++et)
#pragma unroll
            for (int r = 0; r < 4; ++r)
                // C/D layout: col = lane&15, row = (lane>>4)*4 + reg  [m89]
                L[kq][rh * 16 + (lane >> 4) * 4 + r][et * 16 + fr] = acc[rh][et][r];
    __syncthreads();

    {
        const int row = tid >> 3;       // 0..31
        const int eg  = tid & 7;        // 8 experts each
        float v[8];
#pragma unroll
        for (int j = 0; j < 8; ++j)
            v[j] = L[0][row][eg * 8 + j] + L[1][row][eg * 8 + j]
                 + L[2][row][eg * 8 + j] + L[3][row][eg * 8 + j];
        float* dst = part + ((size_t)ks * TN + r0 + row) * EN + eg * 8;
        *reinterpret_cast<float4*>(dst)     = make_float4(v[0], v[1], v[2], v[3]);
        *reinterpret_cast<float4*>(dst + 4) = make_float4(v[4], v[5], v[6], v[7]);
    }
}

// Kernel 2: sum KSPLIT partials, top-1 softmax per row.
// out[0..TN) = argmax index (as float), out[TN..2TN) = max gate = 1/sumexp.
template <int NSPLIT>
__global__ __launch_bounds__(256)
void top1_softmax_kernel(const float* __restrict__ part, float* __restrict__ out) {
    const int row = blockIdx.x * blockDim.x + threadIdx.x;
    if (row >= TN) return;

    float v[EN];
#pragma unroll
    for (int i = 0; i < EN / 4; ++i) {
        float4 s = *reinterpret_cast<const float4*>(&part[(size_t)row * EN + i * 4]);
#pragma unroll
        for (int h = 1; h < NSPLIT; ++h) {
            float4 t = *reinterpret_cast<const float4*>(
                &part[((size_t)h * TN + row) * EN + i * 4]);
            s.x += t.x; s.y += t.y; s.z += t.z; s.w += t.w;
        }
        v[i * 4 + 0] = s.x; v[i * 4 + 1] = s.y;
        v[i * 4 + 2] = s.z; v[i * 4 + 3] = s.w;
    }

    float m = v[0];
    int idx = 0;
#pragma unroll
    for (int e = 1; e < EN; ++e)
        if (v[e] > m) { m = v[e]; idx = e; }  // strict >: first occurrence = jnp.argmax
    float s = 0.0f;
#pragma unroll
    for (int e = 0; e < EN; ++e) s += __expf(v[e] - m);

    out[row]      = (float)idx;
    out[TN + row] = 1.0f / s;
}

extern "C" void kernel_launch(void* const* d_in, const int* in_sizes, int n_in,
                              void* d_out, int out_size, void* d_ws, size_t ws_size,
                              hipStream_t stream) {
    const float* x  = (const float*)d_in[0];
    const float* wg = (const float*)d_in[1];
    float* out = (float*)d_out;

    constexpr size_t BF_BYTES = (size_t)2 * NS * 4 * 512 * 2;  // 1 MB
    unsigned short* BF = (unsigned short*)d_ws;
    float* part = (float*)((char*)d_ws + BF_BYTES);

    wg_frag_kernel<<<dim3(256), dim3(256), 0, stream>>>(wg, BF);

    const size_t need2 = BF_BYTES + (size_t)2 * TN * EN * sizeof(float);  // 5 MB
    if (ws_size >= need2) {
        gate_mfma_kernel<2><<<dim3(256 * 2), dim3(256), 0, stream>>>(x, BF, part);
        top1_softmax_kernel<2><<<dim3(TN / 256), dim3(256), 0, stream>>>(part, out);
    } else {
        gate_mfma_kernel<1><<<dim3(256), dim3(256), 0, stream>>>(x, BF, part);
        top1_softmax_kernel<1><<<dim3(TN / 256), dim3(256), 0, stream>>>(part, out);
    }
}